// Round 22
// baseline (187.056 us; speedup 1.0000x reference)
//
#include <hip/hip_runtime.h>

// GraphDecoder (NRI) — round 31: outmlp7 = outmlp6 with one more TLP step:
// 512 blocks x 4 rows (dup-row via mloc&3, only quad==0 writes) -> 2 blocks/CU
// so each CU overlaps two independent serial chains (the one mechanism that
// reliably paid on every latency-bound non-edge kernel: R16/R17/R22/R26/R30).
// MFMA waste 75% vs a 0.3us FLOP floor — irrelevant. prep (R30) and edge18
// (spill-free, 81.5us stable) byte-identical. B=32,N=64,F=128,K=4,E=4032.

#define B_ 32
#define N_ 64
#define F_ 128
#define K_ 4
#define E_ 4032

// ws layout (bytes): total 9,961,472 <= proven 9,994,240
#define WS_W2T 0u
#define WS_R   524288u
#define WS_S   4718592u
#define WS_AGG 8912896u

typedef unsigned short u16;
typedef u16    u16x4  __attribute__((ext_vector_type(4)));
typedef u16    u16x8  __attribute__((ext_vector_type(8)));
typedef __bf16 bf16x8 __attribute__((ext_vector_type(8)));
typedef float  f32x4  __attribute__((ext_vector_type(4)));
typedef float  f32x16 __attribute__((ext_vector_type(16)));

__device__ __forceinline__ u16 f2bf(float f) {
    unsigned u; __builtin_memcpy(&u, &f, 4);
    return (u16)((u + 0x7FFFu + ((u >> 16) & 1u)) >> 16);
}
__device__ __forceinline__ float bf2f(u16 u) {
    unsigned v = ((unsigned)u) << 16;
    float f; __builtin_memcpy(&f, &v, 4); return f;
}

// raw barrier (LDS-only handoff; keeps vmem prefetch in flight)
#define LBAR() do { \
    asm volatile("s_waitcnt lgkmcnt(0)" ::: "memory"); \
    __builtin_amdgcn_s_barrier(); \
    __builtin_amdgcn_sched_barrier(0); \
} while (0)

// ---------------- fused prep: W2t inline (128/block) + R/S2, 1 c-chunk/block (R30-proven) ----------------
// S2 kk-chunked: S2[((k*8+kc)*2048 + b*64 + row)*32 + kk_local]  (kc = kk>>5)
__global__ __launch_bounds__(256) void prep_rs_kernel(
    const float* __restrict__ W2, const float* __restrict__ x,
    const float* __restrict__ W1, const float* __restrict__ b1,
    u16* __restrict__ W2t, u16* __restrict__ R, u16* __restrict__ S)
{
    __shared__ u16 ldsA[64 * 136];
    __shared__ u16 ldsW[32 * 136];
    const int tid = threadIdx.x;

    if (tid < 128) {   // W2t: linear coalesced read, scattered 2B write
        unsigned gid = blockIdx.x * 128u + tid;
        unsigned n = gid & 255u, kk = (gid >> 8) & 255u, k = gid >> 16;
        unsigned dst = (k * 8u + (kk >> 5)) * 8192u
                     + ((((kk >> 4) & 1u) * 2u) + ((kk >> 3) & 1u)) * 2048u
                     + n * 8u + (kk & 7u);
        W2t[dst] = f2bf(W2[gid]);
    }

    // R/S tables: 2048 blocks = (k, half, b) x ch8; ch covers 1 c-chunk.
    const int lane = tid & 63, w = tid >> 6;
    const int quad = lane >> 4, mloc = lane & 15;
    const int bx = blockIdx.x;
    const int c  = bx & 7;
    const int bq = bx >> 3;
    const int k = bq >> 6, half = (bq >> 5) & 1, b = bq & 31;

    for (int idx = tid; idx < 2048; idx += 256) {
        int row = idx >> 5, c4 = idx & 31;
        f32x4 v = *(const f32x4*)&x[(b * 64 + row) * 128 + c4 * 4];
        u16x4 o;
#pragma unroll
        for (int e = 0; e < 4; ++e) o[e] = f2bf(v[e]);
        *(u16x4*)&ldsA[row * 136 + c4 * 4] = o;
    }
    // ldsW stage (no dependence on ldsA; single barrier covers both)
    for (int idx = tid; idx < 4096; idx += 256) {
        int n = idx & 31, f = idx >> 5;
        ldsW[n * 136 + f] = f2bf(W1[(k * 256 + half * 128 + f) * 256 + c * 32 + n]);
    }
    __syncthreads();

    bf16x8 aF[4];
#pragma unroll
    for (int ks = 0; ks < 4; ++ks)
        aF[ks] = *(const bf16x8*)&ldsA[(w * 16 + mloc) * 136 + quad * 8 + ks * 32];

    u16* dst = half ? S : R;
#pragma unroll
    for (int nt = 0; nt < 2; ++nt) {
        f32x4 acc = (f32x4){0.f, 0.f, 0.f, 0.f};
        const int boff = (nt * 16 + mloc) * 136 + quad * 8;
#pragma unroll
        for (int ks = 0; ks < 4; ++ks)
            acc = __builtin_amdgcn_mfma_f32_16x16x32_bf16(
                aF[ks], *(const bf16x8*)&ldsW[boff + ks * 32], acc, 0, 0, 0);
        const int n = c * 32 + nt * 16 + mloc;
        const float bias = half ? 0.f : b1[k * 256 + n];
#pragma unroll
        for (int r = 0; r < 4; ++r) {
            int row = w * 16 + quad * 4 + r;
            if (half) {
                dst[((size_t)((k * 8 + c) * 2048 + b * 64 + row)) * 32 + nt * 16 + mloc]
                    = f2bf(acc[r] + bias);
            } else {
                dst[((size_t)(k * 2048 + b * 64 + row)) * 256 + n] = f2bf(acc[r] + bias);
            }
        }
    }
}

// ---------------- edge kernel: 2 recv/block, per-kT staged H, inline S loads (R29-proven) ----------------
__global__ __launch_bounds__(256, 2) void edge18_kernel(
    const u16* __restrict__ R, const u16* __restrict__ S2,
    const float* __restrict__ rel, const u16* __restrict__ W2t,
    const float* __restrict__ b2, u16* __restrict__ aggb)
{
    __shared__ u16   Hs[32][128][8];  // H tile for one kT: [g][recv*64+row][8kk] — 64KB
    __shared__ float Rf[2][4][256];   // both receivers' R rows, f32 — 8KB
    __shared__ float rtS[2][4][64];   // rel_type [recv][k][j], self=0 — 2KB

    const int tid  = threadIdx.x;
    const int lane = tid & 63;
    const int w    = tid >> 6;        // n-quarter (MFMA) AND kk32-subgroup (build)
    const int l31  = lane & 31;
    const int lh   = lane >> 5;
    // XCD swizzle for 1024 blocks (bijective: 1024 % 8 == 0)
    const int bid  = ((blockIdx.x & 7) << 7) | (blockIdx.x >> 3);
    const int b    = bid >> 5;
    const int i0   = (bid & 31) * 2;  // receiver pair

    // rtS: self-edge trick, 2 entries/thread
    for (int t = tid; t < 512; t += 256) {
        int recv = t >> 8, rem = t & 255, k = rem >> 6, j = rem & 63;
        int i = i0 + recv;
        float v = 0.f;
        if (j != i) v = rel[((size_t)(b * E_) + i * 63 + (j - (j > i))) * 4 + k];
        rtS[recv][k][j] = v;
    }
    // Rf: both receivers, 8 f32/thread
    {
        int recv = tid >> 7, k = (tid >> 5) & 3, e8 = tid & 31;
        u16x8 t8 = *(const u16x8*)&R[((size_t)(k * 2048 + b * 64 + i0 + recv)) * 256 + e8 * 8];
#pragma unroll
        for (int e = 0; e < 8; ++e) Rf[recv][k][e8 * 8 + e] = bf2f(t8[e]);
    }

    __syncthreads();

    const u16* Wb = W2t + lh * 2048 + (w * 64 + l31) * 8;
    const u16* Sb = S2 + (size_t)(b * 64 + lane) * 32 + w * 8;   // per-lane S base

    float amsg[2][2] = {{0.f, 0.f}, {0.f, 0.f}};

    for (int kT = 0; kT < 4; ++kT) {
        bf16x8 Bb[2][2][2];   // [kc parity][ks2][nt] — static indices
#pragma unroll
        for (int ks2 = 0; ks2 < 2; ++ks2) {
            const u16* wp = Wb + (size_t)(kT * 8) * 8192 + ks2 * 4096;
            Bb[0][ks2][0] = *(const bf16x8*)(wp);
            Bb[0][ks2][1] = *(const bf16x8*)(wp + 256);
        }
        // ---- build H(kT): S loaded inline (transient regs; acc dead here) ----
#pragma unroll
        for (int s = 0; s < 8; ++s) {
            u16x8 sv = *(const u16x8*)(Sb + (size_t)(kT * 8 + s) * 65536);
#pragma unroll
            for (int recv = 0; recv < 2; ++recv) {
                const float* rp = &Rf[recv][kT][s * 32 + w * 8];
                f32x4 r0 = *(const f32x4*)rp, r1 = *(const f32x4*)(rp + 4);
                bf16x8 o;
#pragma unroll
                for (int e = 0; e < 4; ++e) {
                    o[e]     = (__bf16)fmaxf(r0[e] + bf2f(sv[e]),     0.f);
                    o[4 + e] = (__bf16)fmaxf(r1[e] + bf2f(sv[4 + e]), 0.f);
                }
                *(bf16x8*)&Hs[s * 4 + w][recv * 64 + lane][0] = o;
            }
        }
        __syncthreads();   // H(kT) visible

        f32x16 acc[4][2];
#pragma unroll
        for (int mt = 0; mt < 4; ++mt)
#pragma unroll
            for (int nt = 0; nt < 2; ++nt) acc[mt][nt] = (f32x16)(0.f);

#pragma unroll
        for (int kc = 0; kc < 8; ++kc) {
            const int cur = kc & 1, nxt = cur ^ 1;
            // prefetch B(kc+1)
            if (kc < 7) {
#pragma unroll
                for (int ks2 = 0; ks2 < 2; ++ks2) {
                    const u16* wp = Wb + (size_t)(kT * 8 + kc + 1) * 8192 + ks2 * 4096;
                    Bb[nxt][ks2][0] = *(const bf16x8*)(wp);
                    Bb[nxt][ks2][1] = *(const bf16x8*)(wp + 256);
                }
            }
#pragma unroll
            for (int ks2 = 0; ks2 < 2; ++ks2) {
                const int g = kc * 4 + ks2 * 2 + lh;
                bf16x8 A0 = *(const bf16x8*)&Hs[g][l31][0];
                bf16x8 A1 = *(const bf16x8*)&Hs[g][32 + l31][0];
                bf16x8 A2 = *(const bf16x8*)&Hs[g][64 + l31][0];
                bf16x8 A3 = *(const bf16x8*)&Hs[g][96 + l31][0];
                acc[0][0] = __builtin_amdgcn_mfma_f32_32x32x16_bf16(A0, Bb[cur][ks2][0], acc[0][0], 0, 0, 0);
                acc[0][1] = __builtin_amdgcn_mfma_f32_32x32x16_bf16(A0, Bb[cur][ks2][1], acc[0][1], 0, 0, 0);
                acc[1][0] = __builtin_amdgcn_mfma_f32_32x32x16_bf16(A1, Bb[cur][ks2][0], acc[1][0], 0, 0, 0);
                acc[1][1] = __builtin_amdgcn_mfma_f32_32x32x16_bf16(A1, Bb[cur][ks2][1], acc[1][1], 0, 0, 0);
                acc[2][0] = __builtin_amdgcn_mfma_f32_32x32x16_bf16(A2, Bb[cur][ks2][0], acc[2][0], 0, 0, 0);
                acc[2][1] = __builtin_amdgcn_mfma_f32_32x32x16_bf16(A2, Bb[cur][ks2][1], acc[2][1], 0, 0, 0);
                acc[3][0] = __builtin_amdgcn_mfma_f32_32x32x16_bf16(A3, Bb[cur][ks2][0], acc[3][0], 0, 0, 0);
                acc[3][1] = __builtin_amdgcn_mfma_f32_32x32x16_bf16(A3, Bb[cur][ks2][1], acc[3][1], 0, 0, 0);
            }
        }

        // ---- per-kT epilogue: bias + relu + rel_type-weighted row fold ----
#pragma unroll
        for (int nt = 0; nt < 2; ++nt) {
            const float bias = b2[kT * 256 + w * 64 + nt * 32 + l31];
#pragma unroll
            for (int mt = 0; mt < 4; ++mt) {
                const int recv = mt >> 1;
                float s = 0.f;
#pragma unroll
                for (int rq = 0; rq < 4; ++rq) {
                    f32x4 rt4 = *(const f32x4*)&rtS[recv][kT][(mt & 1) * 32 + rq * 8 + 4 * lh];
#pragma unroll
                    for (int e = 0; e < 4; ++e) {
                        float v = acc[mt][nt][rq * 4 + e] + bias;
                        v = v > 0.f ? v : 0.f;
                        s += rt4[e] * v;
                    }
                }
                amsg[recv][nt] += s;
            }
        }
        __syncthreads();
    }

    // fold lh halves; unique writer per slot
#pragma unroll
    for (int recv = 0; recv < 2; ++recv)
#pragma unroll
        for (int nt = 0; nt < 2; ++nt) {
            float s = amsg[recv][nt] + __shfl_xor(amsg[recv][nt], 32);
            if (lh == 0)
                aggb[(size_t)(b * 64 + i0 + recv) * 256 + w * 64 + nt * 32 + l31] = f2bf(s);
        }
}

// ---------------- output MLP: 512 blocks x 4 rows (2 blocks/CU), barrier-free layers ----------------
// Dup-row trick: A rows 4..15 duplicate rows 0..3 (mloc&3); only quad==0 writes.
__global__ __launch_bounds__(256) void outmlp7_kernel(
    const float* __restrict__ x, const u16* __restrict__ aggb,
    const float* __restrict__ Wo1, const float* __restrict__ bo1,
    const float* __restrict__ Wo2, const float* __restrict__ bo2,
    const float* __restrict__ Wo3, const float* __restrict__ bo3,
    float* __restrict__ out)
{
    __shared__ u16 p1S[4 * 264];
    __shared__ u16 p2S[4 * 264];
    const int tid = threadIdx.x, lane = tid & 63, w = tid >> 6;   // w = n-quarter
    const int quad = lane >> 4, mloc = lane & 15;
    const int row0 = blockIdx.x * 4;
    const int arow = row0 + (mloc & 3);    // duplicated A row

    {   // ---- L1: K=384 (12 chunks), N=256, aug=[x|agg] ----
        f32x4 acc[4];
#pragma unroll
        for (int nt = 0; nt < 4; ++nt) acc[nt] = (f32x4){0.f, 0.f, 0.f, 0.f};
        for (int kk = 0; kk < 12; ++kk) {
            bf16x8 aF;
            if (kk < 4) {
                u16x8 t;
#pragma unroll
                for (int e = 0; e < 8; ++e) t[e] = f2bf(x[arow * 128 + kk * 32 + quad * 8 + e]);
                __builtin_memcpy(&aF, &t, 16);
            } else {
                aF = *(const bf16x8*)&aggb[(size_t)arow * 256 + (kk - 4) * 32 + quad * 8];
            }
#pragma unroll
            for (int nt = 0; nt < 4; ++nt) {
                const int n = w * 64 + nt * 16 + mloc;
                u16x8 t;
#pragma unroll
                for (int e = 0; e < 8; ++e)
                    t[e] = f2bf(Wo1[(kk * 32 + quad * 8 + e) * 256 + n]);
                bf16x8 bF;
                __builtin_memcpy(&bF, &t, 16);
                acc[nt] = __builtin_amdgcn_mfma_f32_16x16x32_bf16(aF, bF, acc[nt], 0, 0, 0);
            }
        }
#pragma unroll
        for (int nt = 0; nt < 4; ++nt) {
            const int n = w * 64 + nt * 16 + mloc;
            const float bias = bo1[n];
            if (quad == 0) {
#pragma unroll
                for (int r = 0; r < 4; ++r) {
                    float v = acc[nt][r] + bias;
                    p1S[r * 264 + n] = f2bf(v > 0.f ? v : 0.f);
                }
            }
        }
    }
    LBAR();
    {   // ---- L2: K=256 (8 chunks), N=256 ----
        f32x4 acc[4];
#pragma unroll
        for (int nt = 0; nt < 4; ++nt) acc[nt] = (f32x4){0.f, 0.f, 0.f, 0.f};
        for (int kk = 0; kk < 8; ++kk) {
            bf16x8 aF = *(const bf16x8*)&p1S[(mloc & 3) * 264 + kk * 32 + quad * 8];
#pragma unroll
            for (int nt = 0; nt < 4; ++nt) {
                const int n = w * 64 + nt * 16 + mloc;
                u16x8 t;
#pragma unroll
                for (int e = 0; e < 8; ++e)
                    t[e] = f2bf(Wo2[(kk * 32 + quad * 8 + e) * 256 + n]);
                bf16x8 bF;
                __builtin_memcpy(&bF, &t, 16);
                acc[nt] = __builtin_amdgcn_mfma_f32_16x16x32_bf16(aF, bF, acc[nt], 0, 0, 0);
            }
        }
#pragma unroll
        for (int nt = 0; nt < 4; ++nt) {
            const int n = w * 64 + nt * 16 + mloc;
            const float bias = bo2[n];
            if (quad == 0) {
#pragma unroll
                for (int r = 0; r < 4; ++r) {
                    float v = acc[nt][r] + bias;
                    p2S[r * 264 + n] = f2bf(v > 0.f ? v : 0.f);
                }
            }
        }
    }
    LBAR();
    {   // ---- L3: K=256 (8 chunks), N=128, residual ----
        f32x4 acc[2];
#pragma unroll
        for (int nt = 0; nt < 2; ++nt) acc[nt] = (f32x4){0.f, 0.f, 0.f, 0.f};
        for (int kk = 0; kk < 8; ++kk) {
            bf16x8 aF = *(const bf16x8*)&p2S[(mloc & 3) * 264 + kk * 32 + quad * 8];
#pragma unroll
            for (int nt = 0; nt < 2; ++nt) {
                const int n = w * 32 + nt * 16 + mloc;
                u16x8 t;
#pragma unroll
                for (int e = 0; e < 8; ++e)
                    t[e] = f2bf(Wo3[(kk * 32 + quad * 8 + e) * 128 + n]);
                bf16x8 bF;
                __builtin_memcpy(&bF, &t, 16);
                acc[nt] = __builtin_amdgcn_mfma_f32_16x16x32_bf16(aF, bF, acc[nt], 0, 0, 0);
            }
        }
#pragma unroll
        for (int nt = 0; nt < 2; ++nt) {
            const int n = w * 32 + nt * 16 + mloc;
            const float bias = bo3[n];
            if (quad == 0) {
#pragma unroll
                for (int r = 0; r < 4; ++r) {
                    const int grow = row0 + r;
                    out[grow * 128 + n] = x[grow * 128 + n] + acc[nt][r] + bias;
                }
            }
        }
    }
}

extern "C" void kernel_launch(void* const* d_in, const int* in_sizes, int n_in,
                              void* d_out, int out_size, void* d_ws, size_t ws_size,
                              hipStream_t stream) {
    const float* x   = (const float*)d_in[0];
    const float* rel = (const float*)d_in[1];
    const float* W1  = (const float*)d_in[4];
    const float* b1  = (const float*)d_in[5];
    const float* W2  = (const float*)d_in[6];
    const float* b2  = (const float*)d_in[7];
    const float* Wo1 = (const float*)d_in[8];
    const float* bo1 = (const float*)d_in[9];
    const float* Wo2 = (const float*)d_in[10];
    const float* bo2 = (const float*)d_in[11];
    const float* Wo3 = (const float*)d_in[12];
    const float* bo3 = (const float*)d_in[13];
    float* out = (float*)d_out;

    char* ws = (char*)d_ws;
    u16* W2t  = (u16*)(ws + WS_W2T);
    u16* R    = (u16*)(ws + WS_R);
    u16* S2   = (u16*)(ws + WS_S);
    u16* aggb = (u16*)(ws + WS_AGG);

    prep_rs_kernel<<<2048, 256, 0, stream>>>(W2, x, W1, b1, W2t, R, S2);
    edge18_kernel<<<1024, 256, 0, stream>>>(R, S2, rel, W2t, b2, aggb);
    outmlp7_kernel<<<512, 256, 0, stream>>>(x, aggb, Wo1, bo1, Wo2, bo2, Wo3, bo3, out);
}

// Round 23
// 182.639 us; speedup vs baseline: 1.0242x; 1.0242x over previous
//
#include <hip/hip_runtime.h>

// GraphDecoder (NRI) — round 32 (FINAL): lock in the best-proven config = R30
// (183.1us): prep 2048x1-chunk + W2t inline; edge18 (2 recv/block, per-kT
// staged H, inline S, spill-free: WRITE=1MB, VGPR 124+128, MfmaUtil 35%);
// outmlp6 (256 blocks x 8 rows dup-row). R31's outmlp7 delta (~2us) was
// smaller than the observed cross-acquire variance (edge18 byte-identical
// measured 81.5 vs 88.2) — not chasing noise. Session: 216.9 -> 183.1us.
// B=32, N=64, F=128, K=4, H=M=NH=256, E=4032.

#define B_ 32
#define N_ 64
#define F_ 128
#define K_ 4
#define E_ 4032

// ws layout (bytes): total 9,961,472 <= proven 9,994,240
#define WS_W2T 0u
#define WS_R   524288u
#define WS_S   4718592u
#define WS_AGG 8912896u

typedef unsigned short u16;
typedef u16    u16x4  __attribute__((ext_vector_type(4)));
typedef u16    u16x8  __attribute__((ext_vector_type(8)));
typedef __bf16 bf16x8 __attribute__((ext_vector_type(8)));
typedef float  f32x4  __attribute__((ext_vector_type(4)));
typedef float  f32x16 __attribute__((ext_vector_type(16)));

__device__ __forceinline__ u16 f2bf(float f) {
    unsigned u; __builtin_memcpy(&u, &f, 4);
    return (u16)((u + 0x7FFFu + ((u >> 16) & 1u)) >> 16);
}
__device__ __forceinline__ float bf2f(u16 u) {
    unsigned v = ((unsigned)u) << 16;
    float f; __builtin_memcpy(&f, &v, 4); return f;
}

// raw barrier (LDS-only handoff; keeps vmem prefetch in flight)
#define LBAR() do { \
    asm volatile("s_waitcnt lgkmcnt(0)" ::: "memory"); \
    __builtin_amdgcn_s_barrier(); \
    __builtin_amdgcn_sched_barrier(0); \
} while (0)

// ---------------- fused prep: W2t inline (128/block) + R/S2, 1 c-chunk/block ----------------
// S2 kk-chunked: S2[((k*8+kc)*2048 + b*64 + row)*32 + kk_local]  (kc = kk>>5)
__global__ __launch_bounds__(256) void prep_rs_kernel(
    const float* __restrict__ W2, const float* __restrict__ x,
    const float* __restrict__ W1, const float* __restrict__ b1,
    u16* __restrict__ W2t, u16* __restrict__ R, u16* __restrict__ S)
{
    __shared__ u16 ldsA[64 * 136];
    __shared__ u16 ldsW[32 * 136];
    const int tid = threadIdx.x;

    if (tid < 128) {   // W2t: linear coalesced read, scattered 2B write
        unsigned gid = blockIdx.x * 128u + tid;
        unsigned n = gid & 255u, kk = (gid >> 8) & 255u, k = gid >> 16;
        unsigned dst = (k * 8u + (kk >> 5)) * 8192u
                     + ((((kk >> 4) & 1u) * 2u) + ((kk >> 3) & 1u)) * 2048u
                     + n * 8u + (kk & 7u);
        W2t[dst] = f2bf(W2[gid]);
    }

    // R/S tables: 2048 blocks = (k, half, b) x ch8; ch covers 1 c-chunk.
    const int lane = tid & 63, w = tid >> 6;
    const int quad = lane >> 4, mloc = lane & 15;
    const int bx = blockIdx.x;
    const int c  = bx & 7;
    const int bq = bx >> 3;
    const int k = bq >> 6, half = (bq >> 5) & 1, b = bq & 31;

    for (int idx = tid; idx < 2048; idx += 256) {
        int row = idx >> 5, c4 = idx & 31;
        f32x4 v = *(const f32x4*)&x[(b * 64 + row) * 128 + c4 * 4];
        u16x4 o;
#pragma unroll
        for (int e = 0; e < 4; ++e) o[e] = f2bf(v[e]);
        *(u16x4*)&ldsA[row * 136 + c4 * 4] = o;
    }
    // ldsW stage (no dependence on ldsA; single barrier covers both)
    for (int idx = tid; idx < 4096; idx += 256) {
        int n = idx & 31, f = idx >> 5;
        ldsW[n * 136 + f] = f2bf(W1[(k * 256 + half * 128 + f) * 256 + c * 32 + n]);
    }
    __syncthreads();

    bf16x8 aF[4];
#pragma unroll
    for (int ks = 0; ks < 4; ++ks)
        aF[ks] = *(const bf16x8*)&ldsA[(w * 16 + mloc) * 136 + quad * 8 + ks * 32];

    u16* dst = half ? S : R;
#pragma unroll
    for (int nt = 0; nt < 2; ++nt) {
        f32x4 acc = (f32x4){0.f, 0.f, 0.f, 0.f};
        const int boff = (nt * 16 + mloc) * 136 + quad * 8;
#pragma unroll
        for (int ks = 0; ks < 4; ++ks)
            acc = __builtin_amdgcn_mfma_f32_16x16x32_bf16(
                aF[ks], *(const bf16x8*)&ldsW[boff + ks * 32], acc, 0, 0, 0);
        const int n = c * 32 + nt * 16 + mloc;
        const float bias = half ? 0.f : b1[k * 256 + n];
#pragma unroll
        for (int r = 0; r < 4; ++r) {
            int row = w * 16 + quad * 4 + r;
            if (half) {
                dst[((size_t)((k * 8 + c) * 2048 + b * 64 + row)) * 32 + nt * 16 + mloc]
                    = f2bf(acc[r] + bias);
            } else {
                dst[((size_t)(k * 2048 + b * 64 + row)) * 256 + n] = f2bf(acc[r] + bias);
            }
        }
    }
}

// ---------------- edge kernel: 2 recv/block, per-kT staged H, inline S loads ----------------
__global__ __launch_bounds__(256, 2) void edge18_kernel(
    const u16* __restrict__ R, const u16* __restrict__ S2,
    const float* __restrict__ rel, const u16* __restrict__ W2t,
    const float* __restrict__ b2, u16* __restrict__ aggb)
{
    __shared__ u16   Hs[32][128][8];  // H tile for one kT: [g][recv*64+row][8kk] — 64KB
    __shared__ float Rf[2][4][256];   // both receivers' R rows, f32 — 8KB
    __shared__ float rtS[2][4][64];   // rel_type [recv][k][j], self=0 — 2KB

    const int tid  = threadIdx.x;
    const int lane = tid & 63;
    const int w    = tid >> 6;        // n-quarter (MFMA) AND kk32-subgroup (build)
    const int l31  = lane & 31;
    const int lh   = lane >> 5;
    // XCD swizzle for 1024 blocks (bijective: 1024 % 8 == 0)
    const int bid  = ((blockIdx.x & 7) << 7) | (blockIdx.x >> 3);
    const int b    = bid >> 5;
    const int i0   = (bid & 31) * 2;  // receiver pair

    // rtS: self-edge trick, 2 entries/thread
    for (int t = tid; t < 512; t += 256) {
        int recv = t >> 8, rem = t & 255, k = rem >> 6, j = rem & 63;
        int i = i0 + recv;
        float v = 0.f;
        if (j != i) v = rel[((size_t)(b * E_) + i * 63 + (j - (j > i))) * 4 + k];
        rtS[recv][k][j] = v;
    }
    // Rf: both receivers, 8 f32/thread
    {
        int recv = tid >> 7, k = (tid >> 5) & 3, e8 = tid & 31;
        u16x8 t8 = *(const u16x8*)&R[((size_t)(k * 2048 + b * 64 + i0 + recv)) * 256 + e8 * 8];
#pragma unroll
        for (int e = 0; e < 8; ++e) Rf[recv][k][e8 * 8 + e] = bf2f(t8[e]);
    }

    __syncthreads();

    const u16* Wb = W2t + lh * 2048 + (w * 64 + l31) * 8;
    const u16* Sb = S2 + (size_t)(b * 64 + lane) * 32 + w * 8;   // per-lane S base

    float amsg[2][2] = {{0.f, 0.f}, {0.f, 0.f}};

    for (int kT = 0; kT < 4; ++kT) {
        bf16x8 Bb[2][2][2];   // [kc parity][ks2][nt] — static indices
#pragma unroll
        for (int ks2 = 0; ks2 < 2; ++ks2) {
            const u16* wp = Wb + (size_t)(kT * 8) * 8192 + ks2 * 4096;
            Bb[0][ks2][0] = *(const bf16x8*)(wp);
            Bb[0][ks2][1] = *(const bf16x8*)(wp + 256);
        }
        // ---- build H(kT): S loaded inline (transient regs; acc dead here) ----
#pragma unroll
        for (int s = 0; s < 8; ++s) {
            u16x8 sv = *(const u16x8*)(Sb + (size_t)(kT * 8 + s) * 65536);
#pragma unroll
            for (int recv = 0; recv < 2; ++recv) {
                const float* rp = &Rf[recv][kT][s * 32 + w * 8];
                f32x4 r0 = *(const f32x4*)rp, r1 = *(const f32x4*)(rp + 4);
                bf16x8 o;
#pragma unroll
                for (int e = 0; e < 4; ++e) {
                    o[e]     = (__bf16)fmaxf(r0[e] + bf2f(sv[e]),     0.f);
                    o[4 + e] = (__bf16)fmaxf(r1[e] + bf2f(sv[4 + e]), 0.f);
                }
                *(bf16x8*)&Hs[s * 4 + w][recv * 64 + lane][0] = o;
            }
        }
        __syncthreads();   // H(kT) visible

        f32x16 acc[4][2];
#pragma unroll
        for (int mt = 0; mt < 4; ++mt)
#pragma unroll
            for (int nt = 0; nt < 2; ++nt) acc[mt][nt] = (f32x16)(0.f);

#pragma unroll
        for (int kc = 0; kc < 8; ++kc) {
            const int cur = kc & 1, nxt = cur ^ 1;
            // prefetch B(kc+1)
            if (kc < 7) {
#pragma unroll
                for (int ks2 = 0; ks2 < 2; ++ks2) {
                    const u16* wp = Wb + (size_t)(kT * 8 + kc + 1) * 8192 + ks2 * 4096;
                    Bb[nxt][ks2][0] = *(const bf16x8*)(wp);
                    Bb[nxt][ks2][1] = *(const bf16x8*)(wp + 256);
                }
            }
#pragma unroll
            for (int ks2 = 0; ks2 < 2; ++ks2) {
                const int g = kc * 4 + ks2 * 2 + lh;
                bf16x8 A0 = *(const bf16x8*)&Hs[g][l31][0];
                bf16x8 A1 = *(const bf16x8*)&Hs[g][32 + l31][0];
                bf16x8 A2 = *(const bf16x8*)&Hs[g][64 + l31][0];
                bf16x8 A3 = *(const bf16x8*)&Hs[g][96 + l31][0];
                acc[0][0] = __builtin_amdgcn_mfma_f32_32x32x16_bf16(A0, Bb[cur][ks2][0], acc[0][0], 0, 0, 0);
                acc[0][1] = __builtin_amdgcn_mfma_f32_32x32x16_bf16(A0, Bb[cur][ks2][1], acc[0][1], 0, 0, 0);
                acc[1][0] = __builtin_amdgcn_mfma_f32_32x32x16_bf16(A1, Bb[cur][ks2][0], acc[1][0], 0, 0, 0);
                acc[1][1] = __builtin_amdgcn_mfma_f32_32x32x16_bf16(A1, Bb[cur][ks2][1], acc[1][1], 0, 0, 0);
                acc[2][0] = __builtin_amdgcn_mfma_f32_32x32x16_bf16(A2, Bb[cur][ks2][0], acc[2][0], 0, 0, 0);
                acc[2][1] = __builtin_amdgcn_mfma_f32_32x32x16_bf16(A2, Bb[cur][ks2][1], acc[2][1], 0, 0, 0);
                acc[3][0] = __builtin_amdgcn_mfma_f32_32x32x16_bf16(A3, Bb[cur][ks2][0], acc[3][0], 0, 0, 0);
                acc[3][1] = __builtin_amdgcn_mfma_f32_32x32x16_bf16(A3, Bb[cur][ks2][1], acc[3][1], 0, 0, 0);
            }
        }

        // ---- per-kT epilogue: bias + relu + rel_type-weighted row fold ----
#pragma unroll
        for (int nt = 0; nt < 2; ++nt) {
            const float bias = b2[kT * 256 + w * 64 + nt * 32 + l31];
#pragma unroll
            for (int mt = 0; mt < 4; ++mt) {
                const int recv = mt >> 1;
                float s = 0.f;
#pragma unroll
                for (int rq = 0; rq < 4; ++rq) {
                    f32x4 rt4 = *(const f32x4*)&rtS[recv][kT][(mt & 1) * 32 + rq * 8 + 4 * lh];
#pragma unroll
                    for (int e = 0; e < 4; ++e) {
                        float v = acc[mt][nt][rq * 4 + e] + bias;
                        v = v > 0.f ? v : 0.f;
                        s += rt4[e] * v;
                    }
                }
                amsg[recv][nt] += s;
            }
        }
        __syncthreads();
    }

    // fold lh halves; unique writer per slot
#pragma unroll
    for (int recv = 0; recv < 2; ++recv)
#pragma unroll
        for (int nt = 0; nt < 2; ++nt) {
            float s = amsg[recv][nt] + __shfl_xor(amsg[recv][nt], 32);
            if (lh == 0)
                aggb[(size_t)(b * 64 + i0 + recv) * 256 + w * 64 + nt * 32 + l31] = f2bf(s);
        }
}

// ---------------- output MLP: 256 blocks x 8 rows, barrier-free layers ----------------
__global__ __launch_bounds__(256) void outmlp6_kernel(
    const float* __restrict__ x, const u16* __restrict__ aggb,
    const float* __restrict__ Wo1, const float* __restrict__ bo1,
    const float* __restrict__ Wo2, const float* __restrict__ bo2,
    const float* __restrict__ Wo3, const float* __restrict__ bo3,
    float* __restrict__ out)
{
    __shared__ u16 p1S[8 * 264];
    __shared__ u16 p2S[8 * 264];
    const int tid = threadIdx.x, lane = tid & 63, w = tid >> 6;   // w = n-quarter
    const int quad = lane >> 4, mloc = lane & 15;
    const int row0 = blockIdx.x * 8;
    const int arow = row0 + (mloc & 7);    // duplicated A row

    {   // ---- L1: K=384 (12 chunks), N=256, aug=[x|agg] ----
        f32x4 acc[4];
#pragma unroll
        for (int nt = 0; nt < 4; ++nt) acc[nt] = (f32x4){0.f, 0.f, 0.f, 0.f};
        for (int kk = 0; kk < 12; ++kk) {
            bf16x8 aF;
            if (kk < 4) {
                u16x8 t;
#pragma unroll
                for (int e = 0; e < 8; ++e) t[e] = f2bf(x[arow * 128 + kk * 32 + quad * 8 + e]);
                __builtin_memcpy(&aF, &t, 16);
            } else {
                aF = *(const bf16x8*)&aggb[(size_t)arow * 256 + (kk - 4) * 32 + quad * 8];
            }
#pragma unroll
            for (int nt = 0; nt < 4; ++nt) {
                const int n = w * 64 + nt * 16 + mloc;
                u16x8 t;
#pragma unroll
                for (int e = 0; e < 8; ++e)
                    t[e] = f2bf(Wo1[(kk * 32 + quad * 8 + e) * 256 + n]);
                bf16x8 bF;
                __builtin_memcpy(&bF, &t, 16);
                acc[nt] = __builtin_amdgcn_mfma_f32_16x16x32_bf16(aF, bF, acc[nt], 0, 0, 0);
            }
        }
#pragma unroll
        for (int nt = 0; nt < 4; ++nt) {
            const int n = w * 64 + nt * 16 + mloc;
            const float bias = bo1[n];
            if (quad < 2) {
#pragma unroll
                for (int r = 0; r < 4; ++r) {
                    float v = acc[nt][r] + bias;
                    p1S[(quad * 4 + r) * 264 + n] = f2bf(v > 0.f ? v : 0.f);
                }
            }
        }
    }
    LBAR();
    {   // ---- L2: K=256 (8 chunks), N=256 ----
        f32x4 acc[4];
#pragma unroll
        for (int nt = 0; nt < 4; ++nt) acc[nt] = (f32x4){0.f, 0.f, 0.f, 0.f};
        for (int kk = 0; kk < 8; ++kk) {
            bf16x8 aF = *(const bf16x8*)&p1S[(mloc & 7) * 264 + kk * 32 + quad * 8];
#pragma unroll
            for (int nt = 0; nt < 4; ++nt) {
                const int n = w * 64 + nt * 16 + mloc;
                u16x8 t;
#pragma unroll
                for (int e = 0; e < 8; ++e)
                    t[e] = f2bf(Wo2[(kk * 32 + quad * 8 + e) * 256 + n]);
                bf16x8 bF;
                __builtin_memcpy(&bF, &t, 16);
                acc[nt] = __builtin_amdgcn_mfma_f32_16x16x32_bf16(aF, bF, acc[nt], 0, 0, 0);
            }
        }
#pragma unroll
        for (int nt = 0; nt < 4; ++nt) {
            const int n = w * 64 + nt * 16 + mloc;
            const float bias = bo2[n];
            if (quad < 2) {
#pragma unroll
                for (int r = 0; r < 4; ++r) {
                    float v = acc[nt][r] + bias;
                    p2S[(quad * 4 + r) * 264 + n] = f2bf(v > 0.f ? v : 0.f);
                }
            }
        }
    }
    LBAR();
    {   // ---- L3: K=256 (8 chunks), N=128, residual ----
        f32x4 acc[2];
#pragma unroll
        for (int nt = 0; nt < 2; ++nt) acc[nt] = (f32x4){0.f, 0.f, 0.f, 0.f};
        for (int kk = 0; kk < 8; ++kk) {
            bf16x8 aF = *(const bf16x8*)&p2S[(mloc & 7) * 264 + kk * 32 + quad * 8];
#pragma unroll
            for (int nt = 0; nt < 2; ++nt) {
                const int n = w * 32 + nt * 16 + mloc;
                u16x8 t;
#pragma unroll
                for (int e = 0; e < 8; ++e)
                    t[e] = f2bf(Wo3[(kk * 32 + quad * 8 + e) * 128 + n]);
                bf16x8 bF;
                __builtin_memcpy(&bF, &t, 16);
                acc[nt] = __builtin_amdgcn_mfma_f32_16x16x32_bf16(aF, bF, acc[nt], 0, 0, 0);
            }
        }
#pragma unroll
        for (int nt = 0; nt < 2; ++nt) {
            const int n = w * 32 + nt * 16 + mloc;
            const float bias = bo3[n];
            if (quad < 2) {
#pragma unroll
                for (int r = 0; r < 4; ++r) {
                    const int grow = row0 + quad * 4 + r;
                    out[grow * 128 + n] = x[grow * 128 + n] + acc[nt][r] + bias;
                }
            }
        }
    }
}

extern "C" void kernel_launch(void* const* d_in, const int* in_sizes, int n_in,
                              void* d_out, int out_size, void* d_ws, size_t ws_size,
                              hipStream_t stream) {
    const float* x   = (const float*)d_in[0];
    const float* rel = (const float*)d_in[1];
    const float* W1  = (const float*)d_in[4];
    const float* b1  = (const float*)d_in[5];
    const float* W2  = (const float*)d_in[6];
    const float* b2  = (const float*)d_in[7];
    const float* Wo1 = (const float*)d_in[8];
    const float* bo1 = (const float*)d_in[9];
    const float* Wo2 = (const float*)d_in[10];
    const float* bo2 = (const float*)d_in[11];
    const float* Wo3 = (const float*)d_in[12];
    const float* bo3 = (const float*)d_in[13];
    float* out = (float*)d_out;

    char* ws = (char*)d_ws;
    u16* W2t  = (u16*)(ws + WS_W2T);
    u16* R    = (u16*)(ws + WS_R);
    u16* S2   = (u16*)(ws + WS_S);
    u16* aggb = (u16*)(ws + WS_AGG);

    prep_rs_kernel<<<2048, 256, 0, stream>>>(W2, x, W1, b1, W2t, R, S2);
    edge18_kernel<<<1024, 256, 0, stream>>>(R, S2, rel, W2t, b2, aggb);
    outmlp6_kernel<<<256, 256, 0, stream>>>(x, aggb, Wo1, bo1, Wo2, bo2, Wo3, bo3, out);
}